// Round 10
// baseline (637.770 us; speedup 1.0000x reference)
//
#include <hip/hip_runtime.h>
#include <math.h>
#include <stdint.h>

// Problem constants (B=2, T=2048, D=2048, N=16 q-heads, K=8 kv-heads, G=2, H=128)
// Inputs/outputs are FLOAT32; positions int32; mask bool (unused: causal).
// Internals bf16 (MFMA) with f32 accumulation.
//
// Workspace layout (u16 elements), total 75,497,472 bytes:
//   wqkv_t [32][128][2048]   @ 0              (bf16, transposed; 0..15 Q heads, 16..23 K, 24..31 V)
//   wout_t [2048][2048]      @ 8388608
//   q      [2][16][2048][128]@ 12582912       (roped+scaled, bf16)
//   k      [2][8][2048][128] @ 20971520       (roped, bf16)
//   vt     [2][8][128][2048] @ 25165824       (V transposed: [h][t], bf16)
//   enc    [2][2048][16][128]@ 29360128       (bf16) -- aliased as xb before attn

typedef unsigned short u16;
using bf16x8 = __attribute__((ext_vector_type(8))) short;
using f32x4  = __attribute__((ext_vector_type(4))) float;

#define MFMA_BF16(a,b,c) __builtin_amdgcn_mfma_f32_16x16x32_bf16((a),(b),(c),0,0,0)

static __device__ __forceinline__ float b2f(u16 u) {
  union { unsigned int i; float f; } v; v.i = ((unsigned int)u) << 16; return v.f;
}
static __device__ __forceinline__ u16 f2b(float f) {
  union { float f; unsigned int i; } v; v.f = f;
  unsigned int r = v.i + 0x7fffu + ((v.i >> 16) & 1u);
  return (u16)(r >> 16);
}
// pack two f32 -> bf16x2 dword (round-half-up; inputs are >= 0 softmax weights)
static __device__ __forceinline__ unsigned pk2(float x0, float x1) {
  union { float f; unsigned u; } a, b;
  a.f = x0; b.f = x1;
  return __builtin_amdgcn_perm(b.u + 0x8000u, a.u + 0x8000u, 0x07060302u);
}
// raw v_exp_f32 (arg range here is [-145, 0]; underflow->0 is correct)
static __device__ __forceinline__ float rexp2(float a) {
  float r;
  asm("v_exp_f32 %0, %1" : "=v"(r) : "v"(a));
  return r;
}
static __device__ __forceinline__ void gload_lds16(const void* g, void* l) {
  __builtin_amdgcn_global_load_lds((__attribute__((address_space(1))) void*)(g),
                                   (__attribute__((address_space(3))) void*)(l),
                                   16, 0, 0);
}

// ---------------- prep: x f32->bf16 convert + all weight transposes, one launch ----------------
// blocks [0,8192): convert x (4 f32/thread)
// blocks [8192,12288): transpose w_q     16 x [2048][128] -> [128][2048]
// blocks [12288,16384): transpose w_kv   16 x [2048][128] -> [128][2048]
// blocks [16384,20480): transpose w_out  [2048][2048] -> [2048][2048]
__global__ __launch_bounds__(256) void prep(const float* __restrict__ x, u16* __restrict__ xb,
                                            const float* __restrict__ wq,
                                            const float* __restrict__ wkv,
                                            const float* __restrict__ wout,
                                            u16* __restrict__ wqkvt, u16* __restrict__ woutt) {
  const int tid = threadIdx.x;
  int bid = blockIdx.x;
  if (bid < 8192) {
    const int i = (bid * 256 + tid) * 4;
    const float4 v = *(const float4*)(x + i);
    ushort4 o;
    o.x = f2b(v.x); o.y = f2b(v.y); o.z = f2b(v.z); o.w = f2b(v.w);
    *(ushort4*)(xb + i) = o;
    return;
  }
  bid -= 8192;
  const float* src;
  u16* dst;
  int rows, cols, bx, by;
  if (bid < 8192) {  // wq / wkv: 16 mats each, rows=2048, cols=128, tiles 4 x 64
    const int seg = bid >> 12;              // 0 = wq, 1 = wkv
    const int r = bid & 4095;
    const int mat = r >> 8;
    bx = (r & 255) & 3;
    by = (r & 255) >> 2;
    rows = 2048; cols = 128;
    src = (seg ? wkv : wq) + (size_t)mat * 2048 * 128;
    dst = wqkvt + (size_t)(seg * 16 + mat) * 2048 * 128;
  } else {           // wout: [2048][2048], tiles 64 x 64
    const int r = bid - 8192;
    bx = r & 63;
    by = r >> 6;
    rows = 2048; cols = 2048;
    src = wout;
    dst = woutt;
  }
  __shared__ u16 tile[32][33];
  const int c0 = bx * 32, r0 = by * 32;
  const int tx = tid & 31, ty = tid >> 5;
#pragma unroll
  for (int j = 0; j < 4; ++j)
    tile[ty + j * 8][tx] = f2b(src[(size_t)(r0 + ty + j * 8) * cols + (c0 + tx)]);
  __syncthreads();
#pragma unroll
  for (int j = 0; j < 4; ++j)
    dst[(size_t)(c0 + ty + j * 8) * rows + (r0 + tx)] = tile[tx][ty + j * 8];
}

// ---------------- QKV projection GEMM: 256x256 tile, 8 waves, depth-2 counted-vmcnt pipeline ----
__global__ __launch_bounds__(512, 2) void gemm_qkv(const u16* __restrict__ X,
                                                   const u16* __restrict__ wqkvt,
                                                   u16* __restrict__ qb,
                                                   u16* __restrict__ kb,
                                                   u16* __restrict__ vtb) {
  __shared__ __align__(16) u16 sAB[2][2][16384];  // [buf][A/B][256 rows x 64 cols]
  const int m0 = blockIdx.x * 256;
  const int ct0 = blockIdx.y * 2;
  const u16* BT = wqkvt + (size_t)blockIdx.y * 256 * 2048;
  const int tid = threadIdx.x;
  const int wave = tid >> 6, lane = tid & 63;
  const int wm = wave >> 2, wn = wave & 3;       // 2 M-waves x 4 N-waves
  const int quad = lane >> 4, l16 = lane & 15;
  const int srow = lane >> 3;                    // 0..7 within 8-row group
  const int sch = (lane & 7) ^ srow;             // swizzled 16B chunk 0..7

  f32x4 acc[8][4] = {};

  auto STAGE = [&](int kt, int bsel) {
    const int k0 = kt * 64;
#pragma unroll
    for (int s = 0; s < 4; ++s) {
      const int ia = wave * 4 + s;               // 0..31, each stages 8 rows (1KB)
      const int row = ia * 8 + srow;
      gload_lds16(X + (size_t)(m0 + row) * 2048 + k0 + sch * 8,
                  (char*)&sAB[bsel][0][0] + ia * 1024);
      gload_lds16(BT + (size_t)row * 2048 + k0 + sch * 8,
                  (char*)&sAB[bsel][1][0] + ia * 1024);
    }
  };

  auto COMPUTE = [&](int bsel) {
    const char* aB = (const char*)&sAB[bsel][0][0];
    const char* bB = (const char*)&sAB[bsel][1][0];
#pragma unroll
    for (int ks = 0; ks < 2; ++ks) {
      bf16x8 bfr[4];
#pragma unroll
      for (int nf = 0; nf < 4; ++nf) {
        const int Rb = wn * 64 + nf * 16 + l16;
        bfr[nf] = *(const bf16x8*)(bB + Rb * 128 + (((ks * 4 + quad) ^ (Rb & 7)) << 4));
      }
      __builtin_amdgcn_s_setprio(1);
#pragma unroll
      for (int mf = 0; mf < 8; ++mf) {
        const int R = wm * 128 + mf * 16 + l16;
        const bf16x8 af = *(const bf16x8*)(aB + R * 128 + (((ks * 4 + quad) ^ (R & 7)) << 4));
#pragma unroll
        for (int nf = 0; nf < 4; ++nf)
          acc[mf][nf] = MFMA_BF16(af, bfr[nf], acc[mf][nf]);
      }
      __builtin_amdgcn_s_setprio(0);
    }
  };

  STAGE(0, 0);
#pragma unroll 1
  for (int t = 0; t < 31; ++t) {
    STAGE(t + 1, (t + 1) & 1);
    asm volatile("s_waitcnt vmcnt(8)" ::: "memory");  // tile t landed (wave-local)
    __builtin_amdgcn_s_barrier();                     // all waves' portions landed
    asm volatile("" ::: "memory");
    COMPUTE(t & 1);
    asm volatile("" ::: "memory");
    __builtin_amdgcn_s_barrier();                     // buf[t&1] free for overwrite
    asm volatile("" ::: "memory");
  }
  asm volatile("s_waitcnt vmcnt(0)" ::: "memory");
  __builtin_amdgcn_s_barrier();
  asm volatile("" ::: "memory");
  COMPUTE(1);  // tile 31

  // epilogue: C/D layout row=(quad*4+i), col=l16
#pragma unroll
  for (int mf = 0; mf < 8; ++mf) {
    const int mm = m0 + wm * 128 + mf * 16 + quad * 4;
    const int b = mm >> 11;
    const int t = mm & 2047;
#pragma unroll
    for (int nf = 0; nf < 4; ++nf) {
      const int colg = wn * 64 + nf * 16;        // 0..255 within the B-supertile
      const int ct = ct0 + (colg >> 7);
      const int h = (colg & 127) + l16;
      if (ct < 16) {
        u16* d = qb + (((size_t)b * 16 + ct) * 2048 + t) * 128 + h;
#pragma unroll
        for (int i = 0; i < 4; ++i) d[(size_t)i * 128] = f2b(acc[mf][nf][i]);
      } else if (ct < 24) {
        u16* d = kb + (((size_t)b * 8 + (ct - 16)) * 2048 + t) * 128 + h;
#pragma unroll
        for (int i = 0; i < 4; ++i) d[(size_t)i * 128] = f2b(acc[mf][nf][i]);
      } else {
        u16* d = vtb + (((size_t)b * 8 + (ct - 24)) * 128 + h) * 2048 + t;
        uint2 pkv;
        pkv.x = (unsigned)f2b(acc[mf][nf][0]) | ((unsigned)f2b(acc[mf][nf][1]) << 16);
        pkv.y = (unsigned)f2b(acc[mf][nf][2]) | ((unsigned)f2b(acc[mf][nf][3]) << 16);
        *(uint2*)d = pkv;
      }
    }
  }
}

// ---------------- RoPE (in-place on q and k, bf16; 2 j's per thread) ----------------
__global__ __launch_bounds__(256) void rope_kernel(u16* __restrict__ qb,
                                                   u16* __restrict__ kb,
                                                   const int* __restrict__ pos) {
  const unsigned idx = blockIdx.x * 256 + threadIdx.x;
  const unsigned QP = 1u << 21;  // 2*16*2048*32
  u16* p;
  float scale;
  int b, t, j2;
  if (idx < QP) {
    j2 = (int)(idx & 31) * 2; t = (int)((idx >> 5) & 2047);
    const int hd = (int)((idx >> 16) & 15); b = (int)(idx >> 20);
    p = qb + (((size_t)b * 16 + hd) * 2048 + t) * 128;
    scale = 0.08838834764831845f;  // 1/sqrt(128)
  } else {
    const unsigned r = idx - QP;
    j2 = (int)(r & 31) * 2; t = (int)((r >> 5) & 2047);
    const int hd = (int)((r >> 16) & 7); b = (int)(r >> 19);
    p = kb + (((size_t)b * 8 + hd) * 2048 + t) * 128;
    scale = 1.0f;
  }
  const float fpos = (float)pos[(size_t)b * 2048 + t];
  const unsigned lo = *(const unsigned*)(p + j2);
  const unsigned hi = *(const unsigned*)(p + j2 + 64);
  unsigned olo = 0, ohi = 0;
#pragma unroll
  for (int d = 0; d < 2; ++d) {
    const int j = j2 + d;
    // 1/timescale = 10000^(-j/64) = 2^(-j*log2(1e4)/64)
    const float ang = fpos * exp2f((float)j * -0.2076205059304601f);
    float sn, cs;
    sincosf(ang, &sn, &cs);
    const float a = b2f((u16)((d ? (lo >> 16) : lo) & 0xffffu));
    const float c2 = b2f((u16)((d ? (hi >> 16) : hi) & 0xffffu));
    olo |= ((unsigned)f2b((a * cs - c2 * sn) * scale)) << (16 * d);
    ohi |= ((unsigned)f2b((c2 * cs + a * sn) * scale)) << (16 * d);
  }
  *(unsigned*)(p + j2) = olo;
  *(unsigned*)(p + j2 + 64) = ohi;
}

// ---------------- fused causal attention: t-doubled waves (LDS-BW fix) ----------------
// R9 analysis: attn is LDS-read-bandwidth-bound (~100 B/cy/CU ~= pipe ceiling;
// 1 ds_read_b128 (12cy) per MFMA (5cy)).  Fix: each wave owns 32 t (two 16-col
// groups) so every kfr/vb ds_read feeds 2 MFMAs -> b128 traffic per work halves.
// Geometry: 1024 blocks x 256 thr (4 waves = 2 t-slots x 2 s-halves), QBLK=64,
// KVBLK=64, 32KB LDS, 4 blocks/CU.  Grid map, pairing, K/V staging geometry,
// source-swizzles, and the R8 split-phase counted-vmcnt(4) schedule are
// UNCHANGED.  New: uniform live/mask formulas (d = tw+31-s0w; live iff d>=0 --
// d is only ever -1 or >=31, so frags are all-or-none), and a once-per-block
// cross-s-half O/l reduction through LDS (32KB exact).
// Softcap bounds logits <=50 -> fixed-offset softmax (no max, no O-rescale).
__global__ __launch_bounds__(256, 4) void attn_fused(const u16* __restrict__ qg,
                                                     const u16* __restrict__ kg,
                                                     const u16* __restrict__ vtg,
                                                     u16* __restrict__ enc) {
  __shared__ __align__(16) char lds[32768];
  char* sK = lds;            // [64 s][128 h] bf16, 16B chunks swizzled: ch ^ (row&15)
  char* sV = lds + 16384;    // [128 h][64 s] bf16, 16B chunks swizzled: ch ^ (row&7)

  const int bid = blockIdx.x;
  const int half = bid >> 9;       // 0 = big tile, 1 = small tile of same pair
  const int r = bid & 511;
  const int x = r & 7;             // XCD
  const int g = r >> 3;
  const int pr = g & 15;           // pair rank
  const int head = (g >> 4) * 8 + x;
  const int Q = half ? pr : (31 - pr);
  const int b = head >> 4;
  const int n = head & 15;
  const int kh = n >> 1;

  const u16* qbase = qg + ((size_t)b * 16 + n) * 2048 * 128;
  const u16* kbase = kg + ((size_t)b * 8 + kh) * 2048 * 128;
  const u16* vbase = vtg + ((size_t)b * 8 + kh) * 128 * 2048;

  const int tid = threadIdx.x, wave = tid >> 6, lane = tid & 63;
  const int tslot = wave & 1, shalf = wave >> 1;  // 2 t-slots x 2 s-halves
  const int quad = lane >> 4, l16 = lane & 15;
  const int bp_a0 = ((quad & 1) * 32 + l16) * 4;  // ds_bpermute byte idx, source lane S0
  const int bp_a1 = bp_a0 + 64;                   // source lane S1

  const float L2E = 1.4426950408889634f;
  const float C50 = 72.13475204444817f;  // 50 * log2(e)
  // 50*tanh(x/50)*log2(e) = x*(L2E - B1*u + B2*u^2 - B3*u^3), u = x^2
  const float B1 = 1.9235933879e-4f;   // A1*L2E
  const float B2 = 3.0777494206e-8f;   // A2*L2E
  const float B3 = 4.9830224200e-12f;  // A3*L2E

  // staging source pointers (R8-identical; swizzle folded into global chunk):
  // K: slot j=wave*4+s rows j*4+quad, chunk l16 ^ ((s*4+quad)&15); +64 rows/iter.
  // V: slot j rows j*8+(lane>>3), chunk (lane&7) ^ (lane>>3); +64 cols/iter.
  const u16* kp[4];
  const u16* vp[4];
#pragma unroll
  for (int s = 0; s < 4; ++s) {
    const int kr = wave * 16 + s * 4 + quad;
    kp[s] = kbase + (size_t)kr * 128 + (l16 ^ (s * 4 + quad)) * 8;
    const int vr = wave * 32 + s * 8 + (lane >> 3);
    vp[s] = vbase + (size_t)vr * 2048 + ((lane & 7) ^ (lane >> 3)) * 8;
  }

  const int tw = Q * 64 + tslot * 32;  // wave's 32 t start; groups at tw, tw+16

  // Q B-fragments for both t-groups (n = l16 = t, k contiguous)
  bf16x8 qf[2][4];
#pragma unroll
  for (int gg = 0; gg < 2; ++gg)
#pragma unroll
    for (int kf = 0; kf < 4; ++kf)
      qf[gg][kf] = *(const bf16x8*)(qbase + (size_t)(tw + gg * 16 + l16) * 128 + kf * 32 + quad * 8);

  f32x4 o[2][8] = {};
  f32x4 lacc0 = {0.f, 0.f, 0.f, 0.f};
  f32x4 lacc1 = {0.f, 0.f, 0.f, 0.f};

  // prologue: issue K(0) then V(0)  (order matters for the vmcnt counts)
#pragma unroll
  for (int s = 0; s < 4; ++s) {
    gload_lds16(kp[s], sK + (wave * 4 + s) * 1024);
    kp[s] += 64 * 128;
  }
#pragma unroll
  for (int s = 0; s < 4; ++s) {
    gload_lds16(vp[s], sV + (wave * 4 + s) * 1024);
    vp[s] += 64;
  }

#pragma unroll 1
  for (int si = 0; si <= Q; ++si) {
    const int s0w = si * 64 + shalf * 32;      // wave's 32-s chunk start
    const int dl = tw + 31 - s0w;
    const bool live = dl >= 0;                 // frags all-or-none (dl is -1 or >=31)
    const bool dodiag = (s0w + 31 > tw);

    // outstanding: K(si) 4 oldest + V(si) 4 -> retire K(si)
    asm volatile("s_waitcnt vmcnt(4)" ::: "memory");
    __builtin_amdgcn_s_barrier();              // all waves' K(si) in sK
    asm volatile("" ::: "memory");

    // S^T = K Q^T, both t-groups per kfr read. C: col=t=l16, row=s=quad*4+reg
    f32x4 sa[2][2];                            // [nf][g]
    if (live) {
      __builtin_amdgcn_s_setprio(1);
#pragma unroll
      for (int nf = 0; nf < 2; ++nf) {
        const int sr = shalf * 32 + nf * 16 + l16;
        f32x4 a0 = {0.f, 0.f, 0.f, 0.f};
        f32x4 a1 = {0.f, 0.f, 0.f, 0.f};
#pragma unroll
        for (int kf = 0; kf < 4; ++kf) {
          const bf16x8 kfr =
              *(const bf16x8*)(sK + sr * 256 + (((kf * 4 + quad) ^ (sr & 15)) << 4));
          a0 = MFMA_BF16(kfr, qf[0][kf], a0);
          a1 = MFMA_BF16(kfr, qf[1][kf], a1);
        }
        sa[nf][0] = a0;
        sa[nf][1] = a1;
      }
      __builtin_amdgcn_s_setprio(0);
    }

    asm volatile("" ::: "memory");
    __builtin_amdgcn_s_barrier();              // sK free for overwrite
    asm volatile("" ::: "memory");
    if (si < Q) {                              // K(si+1) lands under softmax+PV
#pragma unroll
      for (int s = 0; s < 4; ++s) {
        gload_lds16(kp[s], sK + (wave * 4 + s) * 1024);
        kp[s] += 64 * 128;
      }
    }

    // poly softcap + fixed-offset exp + mask + l acc + pack (both groups)
    unsigned pkd[2][2][2];
    if (live) {
#pragma unroll
      for (int nf = 0; nf < 2; ++nf) {
#pragma unroll
        for (int gg = 0; gg < 2; ++gg) {
          const f32x4 xv = sa[nf][gg];
          const f32x4 u = xv * xv;
          f32x4 t = u * (-B3) + B2;
          t = u * t + (-B1);
          t = u * t + L2E;                     // log2(e) * tanh(x/50)*50 / x
          f32x4 pv;
#pragma unroll
          for (int i = 0; i < 4; ++i) pv[i] = rexp2(fmaf(xv[i], t[i], -C50));
          if (dodiag) {
            const int tl = tw + gg * 16 + l16;
#pragma unroll
            for (int i = 0; i < 4; ++i) {
              const int sg = s0w + nf * 16 + quad * 4 + i;
              if (sg > tl) pv[i] = 0.0f;
            }
          }
          if (gg == 0) lacc0 += pv; else lacc1 += pv;
          pkd[gg][nf][0] = pk2(pv[0], pv[1]);
          pkd[gg][nf][1] = pk2(pv[2], pv[3]);
        }
      }
    }

    // P^T B-fragments via bpermute (wave's own 32-s chunk = its 2 frags)
    union { int d[4]; bf16x8 v; } pb[2];
    if (live) {
      const int lo = (quad >> 1);
#pragma unroll
      for (int gg = 0; gg < 2; ++gg) {
        const int dA0 = __builtin_amdgcn_ds_bpermute(bp_a0, (int)pkd[gg][0][0]);
        const int dB0 = __builtin_amdgcn_ds_bpermute(bp_a0, (int)pkd[gg][1][0]);
        const int dA1 = __builtin_amdgcn_ds_bpermute(bp_a0, (int)pkd[gg][0][1]);
        const int dB1 = __builtin_amdgcn_ds_bpermute(bp_a0, (int)pkd[gg][1][1]);
        const int dA2 = __builtin_amdgcn_ds_bpermute(bp_a1, (int)pkd[gg][0][0]);
        const int dB2 = __builtin_amdgcn_ds_bpermute(bp_a1, (int)pkd[gg][1][0]);
        const int dA3 = __builtin_amdgcn_ds_bpermute(bp_a1, (int)pkd[gg][0][1]);
        const int dB3 = __builtin_amdgcn_ds_bpermute(bp_a1, (int)pkd[gg][1][1]);
        pb[gg].d[0] = lo ? dB0 : dA0;
        pb[gg].d[1] = lo ? dB1 : dA1;
        pb[gg].d[2] = lo ? dB2 : dA2;
        pb[gg].d[3] = lo ? dB3 : dA3;
      }
    }

    // outstanding: V(si) 4 oldest + K(si+1) 4 -> retire V(si); last iter: drain
    if (si < Q) {
      asm volatile("s_waitcnt vmcnt(4)" ::: "memory");
    } else {
      asm volatile("s_waitcnt vmcnt(0)" ::: "memory");
    }
    __builtin_amdgcn_s_barrier();              // all waves' V(si) in sV
    asm volatile("" ::: "memory");

    // O^T += V^T P^T : wave's chunk = shalf; both t-groups per vb read
    if (live) {
      __builtin_amdgcn_s_setprio(1);
#pragma unroll
      for (int nfo = 0; nfo < 8; ++nfo) {
        const int hr = nfo * 16 + l16;
        const bf16x8 vb =
            *(const bf16x8*)(sV + hr * 128 + (((shalf * 4 + quad) ^ (hr & 7)) << 4));
        o[0][nfo] = MFMA_BF16(vb, pb[0].v, o[0][nfo]);
        o[1][nfo] = MFMA_BF16(vb, pb[1].v, o[1][nfo]);
      }
      __builtin_amdgcn_s_setprio(0);
    }

    asm volatile("" ::: "memory");
    __builtin_amdgcn_s_barrier();              // sV free for overwrite
    asm volatile("" ::: "memory");
    if (si < Q) {                              // V(si+1) lands under next QK^T
#pragma unroll
      for (int s = 0; s < 4; ++s) {
        gload_lds16(vp[s], sV + (wave * 4 + s) * 1024);
        vp[s] += 64;
      }
    }
  }

  // ---- epilogue: cross-s-half reduction (partner wave = wave ^ 2) ----
  float lsum0 = lacc0[0] + lacc0[1] + lacc0[2] + lacc0[3];
  lsum0 += __shfl_xor(lsum0, 16); lsum0 += __shfl_xor(lsum0, 32);
  float lsum1 = lacc1[0] + lacc1[1] + lacc1[2] + lacc1[3];
  lsum1 += __shfl_xor(lsum1, 16); lsum1 += __shfl_xor(lsum1, 32);

  float* red = (float*)lds;
  __syncthreads();
  if (lane < 16) {
    red[(wave * 2 + 0) * 16 + lane] = lsum0;
    red[(wave * 2 + 1) * 16 + lane] = lsum1;
  }
  __syncthreads();
  const int pw = wave ^ 2;
  lsum0 += red[(pw * 2 + 0) * 16 + l16];
  lsum1 += red[(pw * 2 + 1) * 16 + l16];
  __syncthreads();
  // o: shalf==1 waves park their partial O in LDS (2 waves x 16KB = 32KB exact)
  if (shalf) {
#pragma unroll
    for (int gg = 0; gg < 2; ++gg)
#pragma unroll
      for (int nfo = 0; nfo < 8; ++nfo)
        *(f32x4*)(lds + (((tslot * 2 + gg) * 8 + nfo) * 1024) + lane * 16) = o[gg][nfo];
  }
  __syncthreads();
  if (!shalf) {
#pragma unroll
    for (int gg = 0; gg < 2; ++gg) {
      const float inv = 1.0f / (gg ? lsum1 : lsum0);
      const int tlg = tw + gg * 16 + l16;
      u16* d = enc + (((size_t)b * 2048 + tlg) * 16 + n) * 128 + quad * 4;
#pragma unroll
      for (int nfo = 0; nfo < 8; ++nfo) {
        f32x4 ov = o[gg][nfo];
        ov += *(const f32x4*)(lds + (((tslot * 2 + gg) * 8 + nfo) * 1024) + lane * 16);
        uint2 st;
        st.x = (unsigned)f2b(ov[0] * inv) | ((unsigned)f2b(ov[1] * inv) << 16);
        st.y = (unsigned)f2b(ov[2] * inv) | ((unsigned)f2b(ov[3] * inv) << 16);
        *(uint2*)(d + nfo * 16) = st;
      }
    }
  }
}

// ---------------- output projection GEMM: 256x128 tile, 8 waves, depth-2 pipeline, f32 out ----
__global__ __launch_bounds__(512, 2) void gemm_out(const u16* __restrict__ A,
                                                   const u16* __restrict__ Bt,
                                                   float* __restrict__ C) {
  __shared__ __align__(16) u16 sA[2][16384];  // [buf][256 rows x 64 cols]
  __shared__ __align__(16) u16 sB[2][8192];   // [buf][128 rows x 64 cols]
  const int m0 = blockIdx.x * 256;
  const int n0 = blockIdx.y * 128;
  const int tid = threadIdx.x;
  const int wave = tid >> 6, lane = tid & 63;
  const int wm = wave >> 2, wn = wave & 3;       // 2 M-waves x 4 N-waves (per-wave 128x32)
  const int quad = lane >> 4, l16 = lane & 15;
  const int srow = lane >> 3;
  const int sch = (lane & 7) ^ srow;

  f32x4 acc[8][2] = {};

  auto STAGE = [&](int kt, int bsel) {
    const int k0 = kt * 64;
#pragma unroll
    for (int s = 0; s < 4; ++s) {
      const int ia = wave * 4 + s;               // 0..31
      const int row = ia * 8 + srow;             // 0..255
      gload_lds16(A + (size_t)(m0 + row) * 2048 + k0 + sch * 8,
                  (char*)&sA[bsel][0] + ia * 1024);
    }
#pragma unroll
    for (int s = 0; s < 2; ++s) {
      const int ib = wave * 2 + s;               // 0..15
      const int row = ib * 8 + srow;             // 0..127
      gload_lds16(Bt + (size_t)(n0 + row) * 2048 + k0 + sch * 8,
                  (char*)&sB[bsel][0] + ib * 1024);
    }
  };

  auto COMPUTE = [&](int bsel) {
    const char* aB = (const char*)&sA[bsel][0];
    const char* bB = (const char*)&sB[bsel][0];
#pragma unroll
    for (int ks = 0; ks < 2; ++ks) {
      bf16x8 bfr[2];
#pragma unroll
      for (int nf = 0; nf < 2; ++nf) {
        const int Rb = wn * 32 + nf * 16 + l16;
        bfr[nf] = *(const bf16x8*)(bB + Rb * 128 + (((ks * 4 + quad) ^ (Rb & 7)) << 4));
      }
      __builtin_amdgcn_s_setprio(1);
#pragma unroll
      for (int mf = 0; mf < 8; ++mf) {
        const int R = wm * 128 + mf * 16 + l16;
        const bf16x8 af = *(const bf16x8*)(aB + R * 128 + (((ks * 4 + quad) ^ (R & 7)) << 4));
#pragma unroll
        for (int nf = 0; nf < 2; ++nf)
          acc[mf][nf] = MFMA_BF16(af, bfr[nf], acc[mf][nf]);
      }
      __builtin_amdgcn_s_setprio(0);
    }
  };

  STAGE(0, 0);
#pragma unroll 1
  for (int t = 0; t < 31; ++t) {
    STAGE(t + 1, (t + 1) & 1);
    asm volatile("s_waitcnt vmcnt(6)" ::: "memory");  // tile t landed (wave-local)
    __builtin_amdgcn_s_barrier();
    asm volatile("" ::: "memory");
    COMPUTE(t & 1);
    asm volatile("" ::: "memory");
    __builtin_amdgcn_s_barrier();
    asm volatile("" ::: "memory");
  }
  asm volatile("s_waitcnt vmcnt(0)" ::: "memory");
  __builtin_amdgcn_s_barrier();
  asm volatile("" ::: "memory");
  COMPUTE(1);  // tile 31

#pragma unroll
  for (int mf = 0; mf < 8; ++mf) {
    const int mm = m0 + wm * 128 + mf * 16 + quad * 4;
#pragma unroll
    for (int nf = 0; nf < 2; ++nf) {
      const int col = n0 + wn * 32 + nf * 16 + l16;
#pragma unroll
      for (int i = 0; i < 4; ++i) C[(size_t)(mm + i) * 2048 + col] = acc[mf][nf][i];
    }
  }
}

extern "C" void kernel_launch(void* const* d_in, const int* in_sizes, int n_in,
                              void* d_out, int out_size, void* d_ws, size_t ws_size,
                              hipStream_t stream) {
  (void)in_sizes; (void)n_in; (void)out_size; (void)ws_size;
  const float* x     = (const float*)d_in[0];
  const int*   posi  = (const int*)d_in[1];
  const float* w_q   = (const float*)d_in[3];
  const float* w_kv  = (const float*)d_in[4];
  const float* w_out = (const float*)d_in[5];
  float* out = (float*)d_out;

  u16* ws = (u16*)d_ws;
  u16* wqkvt = ws;
  u16* woutt = ws + (size_t)8388608;
  u16* qb    = ws + (size_t)12582912;
  u16* kb    = ws + (size_t)20971520;
  u16* vtb   = ws + (size_t)25165824;
  u16* encb  = ws + (size_t)29360128;
  u16* xb    = encb;  // alias: consumed by gemm_qkv before attn writes enc

  prep<<<20480, 256, 0, stream>>>(x, xb, w_q, w_kv, w_out, wqkvt, woutt);
  gemm_qkv<<<dim3(16, 16), 512, 0, stream>>>(xb, wqkvt, qb, kb, vtb);
  rope_kernel<<<12288, 256, 0, stream>>>(qb, kb, posi);
  attn_fused<<<1024, 256, 0, stream>>>(qb, kb, vtb, encb);
  gemm_out<<<dim3(16, 16), 512, 0, stream>>>(encb, woutt, out);
}

// Round 11
// 333.331 us; speedup vs baseline: 1.9133x; 1.9133x over previous
//
#include <hip/hip_runtime.h>
#include <math.h>
#include <stdint.h>

// Problem constants (B=2, T=2048, D=2048, N=16 q-heads, K=8 kv-heads, G=2, H=128)
// Inputs/outputs are FLOAT32; positions int32; mask bool (unused: causal).
// Internals bf16 (MFMA) with f32 accumulation.
//
// Workspace layout (u16 elements), total 75,497,472 bytes:
//   wqkv_t [32][128][2048]   @ 0              (bf16, transposed; 0..15 Q heads, 16..23 K, 24..31 V)
//   wout_t [2048][2048]      @ 8388608
//   q      [2][16][2048][128]@ 12582912       (roped+scaled, bf16)
//   k      [2][8][2048][128] @ 20971520       (roped, bf16)
//   vt     [2][8][128][2048] @ 25165824       (V transposed: [h][t], bf16)
//   enc    [2][2048][16][128]@ 29360128       (bf16) -- aliased as xb before attn

typedef unsigned short u16;
using bf16x8 = __attribute__((ext_vector_type(8))) short;
using f32x4  = __attribute__((ext_vector_type(4))) float;

#define MFMA_BF16(a,b,c) __builtin_amdgcn_mfma_f32_16x16x32_bf16((a),(b),(c),0,0,0)

static __device__ __forceinline__ float b2f(u16 u) {
  union { unsigned int i; float f; } v; v.i = ((unsigned int)u) << 16; return v.f;
}
static __device__ __forceinline__ u16 f2b(float f) {
  union { float f; unsigned int i; } v; v.f = f;
  unsigned int r = v.i + 0x7fffu + ((v.i >> 16) & 1u);
  return (u16)(r >> 16);
}
// pack two f32 -> bf16x2 dword (round-half-up; inputs are >= 0 softmax weights)
static __device__ __forceinline__ unsigned pk2(float x0, float x1) {
  union { float f; unsigned u; } a, b;
  a.f = x0; b.f = x1;
  return __builtin_amdgcn_perm(b.u + 0x8000u, a.u + 0x8000u, 0x07060302u);
}
// raw v_exp_f32 (arg range here is [-145, 0]; underflow->0 is correct)
static __device__ __forceinline__ float rexp2(float a) {
  float r;
  asm("v_exp_f32 %0, %1" : "=v"(r) : "v"(a));
  return r;
}
static __device__ __forceinline__ void gload_lds16(const void* g, void* l) {
  __builtin_amdgcn_global_load_lds((__attribute__((address_space(1))) void*)(g),
                                   (__attribute__((address_space(3))) void*)(l),
                                   16, 0, 0);
}

// ---------------- prep: x f32->bf16 convert + all weight transposes, one launch ----------------
// blocks [0,8192): convert x (4 f32/thread)
// blocks [8192,12288): transpose w_q     16 x [2048][128] -> [128][2048]
// blocks [12288,16384): transpose w_kv   16 x [2048][128] -> [128][2048]
// blocks [16384,20480): transpose w_out  [2048][2048] -> [2048][2048]
__global__ __launch_bounds__(256) void prep(const float* __restrict__ x, u16* __restrict__ xb,
                                            const float* __restrict__ wq,
                                            const float* __restrict__ wkv,
                                            const float* __restrict__ wout,
                                            u16* __restrict__ wqkvt, u16* __restrict__ woutt) {
  const int tid = threadIdx.x;
  int bid = blockIdx.x;
  if (bid < 8192) {
    const int i = (bid * 256 + tid) * 4;
    const float4 v = *(const float4*)(x + i);
    ushort4 o;
    o.x = f2b(v.x); o.y = f2b(v.y); o.z = f2b(v.z); o.w = f2b(v.w);
    *(ushort4*)(xb + i) = o;
    return;
  }
  bid -= 8192;
  const float* src;
  u16* dst;
  int rows, cols, bx, by;
  if (bid < 8192) {  // wq / wkv: 16 mats each, rows=2048, cols=128, tiles 4 x 64
    const int seg = bid >> 12;              // 0 = wq, 1 = wkv
    const int r = bid & 4095;
    const int mat = r >> 8;
    bx = (r & 255) & 3;
    by = (r & 255) >> 2;
    rows = 2048; cols = 128;
    src = (seg ? wkv : wq) + (size_t)mat * 2048 * 128;
    dst = wqkvt + (size_t)(seg * 16 + mat) * 2048 * 128;
  } else {           // wout: [2048][2048], tiles 64 x 64
    const int r = bid - 8192;
    bx = r & 63;
    by = r >> 6;
    rows = 2048; cols = 2048;
    src = wout;
    dst = woutt;
  }
  __shared__ u16 tile[32][33];
  const int c0 = bx * 32, r0 = by * 32;
  const int tx = tid & 31, ty = tid >> 5;
#pragma unroll
  for (int j = 0; j < 4; ++j)
    tile[ty + j * 8][tx] = f2b(src[(size_t)(r0 + ty + j * 8) * cols + (c0 + tx)]);
  __syncthreads();
#pragma unroll
  for (int j = 0; j < 4; ++j)
    dst[(size_t)(c0 + ty + j * 8) * rows + (r0 + tx)] = tile[tx][ty + j * 8];
}

// ---------------- QKV projection GEMM: 256x256 tile, 8 waves, depth-2 counted-vmcnt pipeline ----
// C[m][h] = sum_d X[m][d] * Wt[h][d].  B-supertile spans 2 consecutive head
// matrices (wqkvt is contiguous across heads, so BT rows are just n0..n0+255).
// LDS: 2 buffers x (A 32KB + B 32KB) = 128KB.  Tile rows are 128B = 8 x 16B
// chunks, swizzled ch ^ (row&7) on the global-source side (global_load_lds
// pins LDS slot = lane*16).  K-loop uses raw s_barrier + hand-placed
// s_waitcnt vmcnt(8): tile t+1's 8 loads stay in flight across the barrier
// and land under tile t's compute (T3/T4).
__global__ __launch_bounds__(512, 2) void gemm_qkv(const u16* __restrict__ X,
                                                   const u16* __restrict__ wqkvt,
                                                   u16* __restrict__ qb,
                                                   u16* __restrict__ kb,
                                                   u16* __restrict__ vtb) {
  __shared__ __align__(16) u16 sAB[2][2][16384];  // [buf][A/B][256 rows x 64 cols]
  const int m0 = blockIdx.x * 256;
  const int ct0 = blockIdx.y * 2;
  const u16* BT = wqkvt + (size_t)blockIdx.y * 256 * 2048;
  const int tid = threadIdx.x;
  const int wave = tid >> 6, lane = tid & 63;
  const int wm = wave >> 2, wn = wave & 3;       // 2 M-waves x 4 N-waves
  const int quad = lane >> 4, l16 = lane & 15;
  const int srow = lane >> 3;                    // 0..7 within 8-row group
  const int sch = (lane & 7) ^ srow;             // swizzled 16B chunk 0..7

  f32x4 acc[8][4] = {};

  auto STAGE = [&](int kt, int bsel) {
    const int k0 = kt * 64;
#pragma unroll
    for (int s = 0; s < 4; ++s) {
      const int ia = wave * 4 + s;               // 0..31, each stages 8 rows (1KB)
      const int row = ia * 8 + srow;
      gload_lds16(X + (size_t)(m0 + row) * 2048 + k0 + sch * 8,
                  (char*)&sAB[bsel][0][0] + ia * 1024);
      gload_lds16(BT + (size_t)row * 2048 + k0 + sch * 8,
                  (char*)&sAB[bsel][1][0] + ia * 1024);
    }
  };

  auto COMPUTE = [&](int bsel) {
    const char* aB = (const char*)&sAB[bsel][0][0];
    const char* bB = (const char*)&sAB[bsel][1][0];
#pragma unroll
    for (int ks = 0; ks < 2; ++ks) {
      bf16x8 bfr[4];
#pragma unroll
      for (int nf = 0; nf < 4; ++nf) {
        const int Rb = wn * 64 + nf * 16 + l16;
        bfr[nf] = *(const bf16x8*)(bB + Rb * 128 + (((ks * 4 + quad) ^ (Rb & 7)) << 4));
      }
      __builtin_amdgcn_s_setprio(1);
#pragma unroll
      for (int mf = 0; mf < 8; ++mf) {
        const int R = wm * 128 + mf * 16 + l16;
        const bf16x8 af = *(const bf16x8*)(aB + R * 128 + (((ks * 4 + quad) ^ (R & 7)) << 4));
#pragma unroll
        for (int nf = 0; nf < 4; ++nf)
          acc[mf][nf] = MFMA_BF16(af, bfr[nf], acc[mf][nf]);
      }
      __builtin_amdgcn_s_setprio(0);
    }
  };

  STAGE(0, 0);
#pragma unroll 1
  for (int t = 0; t < 31; ++t) {
    STAGE(t + 1, (t + 1) & 1);
    asm volatile("s_waitcnt vmcnt(8)" ::: "memory");  // tile t landed (wave-local)
    __builtin_amdgcn_s_barrier();                     // all waves' portions landed
    asm volatile("" ::: "memory");
    COMPUTE(t & 1);
    asm volatile("" ::: "memory");
    __builtin_amdgcn_s_barrier();                     // buf[t&1] free for overwrite
    asm volatile("" ::: "memory");
  }
  asm volatile("s_waitcnt vmcnt(0)" ::: "memory");
  __builtin_amdgcn_s_barrier();
  asm volatile("" ::: "memory");
  COMPUTE(1);  // tile 31

  // epilogue: C/D layout row=(quad*4+i), col=l16
#pragma unroll
  for (int mf = 0; mf < 8; ++mf) {
    const int mm = m0 + wm * 128 + mf * 16 + quad * 4;
    const int b = mm >> 11;
    const int t = mm & 2047;
#pragma unroll
    for (int nf = 0; nf < 4; ++nf) {
      const int colg = wn * 64 + nf * 16;        // 0..255 within the B-supertile
      const int ct = ct0 + (colg >> 7);
      const int h = (colg & 127) + l16;
      if (ct < 16) {
        u16* d = qb + (((size_t)b * 16 + ct) * 2048 + t) * 128 + h;
#pragma unroll
        for (int i = 0; i < 4; ++i) d[(size_t)i * 128] = f2b(acc[mf][nf][i]);
      } else if (ct < 24) {
        u16* d = kb + (((size_t)b * 8 + (ct - 16)) * 2048 + t) * 128 + h;
#pragma unroll
        for (int i = 0; i < 4; ++i) d[(size_t)i * 128] = f2b(acc[mf][nf][i]);
      } else {
        u16* d = vtb + (((size_t)b * 8 + (ct - 24)) * 128 + h) * 2048 + t;
        uint2 pkv;
        pkv.x = (unsigned)f2b(acc[mf][nf][0]) | ((unsigned)f2b(acc[mf][nf][1]) << 16);
        pkv.y = (unsigned)f2b(acc[mf][nf][2]) | ((unsigned)f2b(acc[mf][nf][3]) << 16);
        *(uint2*)d = pkv;
      }
    }
  }
}

// ---------------- RoPE (in-place on q and k, bf16; 2 j's per thread) ----------------
__global__ __launch_bounds__(256) void rope_kernel(u16* __restrict__ qb,
                                                   u16* __restrict__ kb,
                                                   const int* __restrict__ pos) {
  const unsigned idx = blockIdx.x * 256 + threadIdx.x;
  const unsigned QP = 1u << 21;  // 2*16*2048*32
  u16* p;
  float scale;
  int b, t, j2;
  if (idx < QP) {
    j2 = (int)(idx & 31) * 2; t = (int)((idx >> 5) & 2047);
    const int hd = (int)((idx >> 16) & 15); b = (int)(idx >> 20);
    p = qb + (((size_t)b * 16 + hd) * 2048 + t) * 128;
    scale = 0.08838834764831845f;  // 1/sqrt(128)
  } else {
    const unsigned r = idx - QP;
    j2 = (int)(r & 31) * 2; t = (int)((r >> 5) & 2047);
    const int hd = (int)((r >> 16) & 7); b = (int)(r >> 19);
    p = kb + (((size_t)b * 8 + hd) * 2048 + t) * 128;
    scale = 1.0f;
  }
  const float fpos = (float)pos[(size_t)b * 2048 + t];
  const unsigned lo = *(const unsigned*)(p + j2);
  const unsigned hi = *(const unsigned*)(p + j2 + 64);
  unsigned olo = 0, ohi = 0;
#pragma unroll
  for (int d = 0; d < 2; ++d) {
    const int j = j2 + d;
    // 1/timescale = 10000^(-j/64) = 2^(-j*log2(1e4)/64)
    const float ang = fpos * exp2f((float)j * -0.2076205059304601f);
    float sn, cs;
    sincosf(ang, &sn, &cs);
    const float a = b2f((u16)((d ? (lo >> 16) : lo) & 0xffffu));
    const float c2 = b2f((u16)((d ? (hi >> 16) : hi) & 0xffffu));
    olo |= ((unsigned)f2b((a * cs - c2 * sn) * scale)) << (16 * d);
    ohi |= ((unsigned)f2b((c2 * cs + a * sn) * scale)) << (16 * d);
  }
  *(unsigned*)(p + j2) = olo;
  *(unsigned*)(p + j2 + 64) = ohi;
}

// ---------------- fused causal attention, S^T formulation, split-phase K/V pipeline ----------------
// R8-VERIFIED BEST (76.6us).  1024 blocks x 256 thr, one 64-row q-tile per
// block, 4 blocks/CU (32KB LDS, 56 VGPR).  Structural escape attempts all
// failed: R3 LDS-dbuf (-occupancy), R6 reg-stage (scratch spill), R9 fat
// tiles (neutral), R10 t-double (spill: o[2][8]+qf[2][4] > 128 VGPR budget).
// Blocks [0,512) big tiles (Q=31-pr, issued first), [512,1024) the small tile
// of the SAME pair (Q=pr).  Low 3 bits = XCD for K/V L2 locality.
// QK^T only reads sK and PV only reads sV, so K(si+1) is issued right after
// QK^T(si)'s trailing barrier (lands under softmax+PV), and V(si+1) right
// after PV(si)'s trailing barrier (lands under next QK^T).  Every wait is a
// counted s_waitcnt vmcnt(4) -- the other phase's 4 loads stay in flight.
// Softcap bounds logits <=50 -> fixed-offset softmax (no max, no O-rescale),
// exp2 poly has L2E pre-folded, raw v_exp_f32 (arg in [-145,0], uflow->0 ok).
__global__ __launch_bounds__(256, 4) void attn_fused(const u16* __restrict__ qg,
                                                     const u16* __restrict__ kg,
                                                     const u16* __restrict__ vtg,
                                                     u16* __restrict__ enc) {
  __shared__ __align__(16) char lds[32768];
  char* sK = lds;            // [64 s][128 h] bf16, 16B chunks swizzled: ch ^ (row&15)
  char* sV = lds + 16384;    // [128 h][64 s] bf16, 16B chunks swizzled: ch ^ (row&7)

  const int bid = blockIdx.x;
  const int half = bid >> 9;       // 0 = big tile, 1 = small tile of same pair
  const int r = bid & 511;
  const int x = r & 7;             // XCD
  const int g = r >> 3;
  const int pr = g & 15;           // pair rank
  const int head = (g >> 4) * 8 + x;
  const int Q = half ? pr : (31 - pr);
  const int b = head >> 4;
  const int n = head & 15;
  const int kh = n >> 1;

  const u16* qbase = qg + ((size_t)b * 16 + n) * 2048 * 128;
  const u16* kbase = kg + ((size_t)b * 8 + kh) * 2048 * 128;
  const u16* vbase = vtg + ((size_t)b * 8 + kh) * 128 * 2048;

  const int tid = threadIdx.x, wave = tid >> 6, lane = tid & 63;
  const int quad = lane >> 4, l16 = lane & 15;
  const int bp_a0 = ((quad & 1) * 32 + l16) * 4;  // ds_bpermute byte idx, source lane S0
  const int bp_a1 = bp_a0 + 64;                   // source lane S1

  const float L2E = 1.4426950408889634f;
  const float C50 = 72.13475204444817f;  // 50 * log2(e)
  // 50*tanh(x/50)*log2(e) = x*(L2E - B1*u + B2*u^2 - B3*u^3), u = x^2
  const float B1 = 1.9235933879e-4f;   // A1*L2E
  const float B2 = 3.0777494206e-8f;   // A2*L2E
  const float B3 = 4.9830224200e-12f;  // A3*L2E

  // staging source pointers (swizzle folded into the global-side chunk index):
  // K: instr j=wave*4+s covers rows j*4+quad, LDS slot l16 must hold global
  //    chunk l16 ^ ((s*4+quad)&15).  advance 64 rows (8192 elems) per s-iter.
  // V: instr j covers rows j*8+(lane>>3), LDS slot (lane&7) must hold global
  //    chunk (lane&7) ^ (lane>>3).   advance 64 elems (s0) per s-iter.
  const u16* kp[4];
  const u16* vp[4];
#pragma unroll
  for (int s = 0; s < 4; ++s) {
    const int kr = wave * 16 + s * 4 + quad;
    kp[s] = kbase + (size_t)kr * 128 + (l16 ^ (s * 4 + quad)) * 8;
    const int vr = wave * 32 + s * 8 + (lane >> 3);
    vp[s] = vbase + (size_t)vr * 2048 + ((lane & 7) ^ (lane >> 3)) * 8;
  }

  const int tw = Q * 64 + wave * 16;   // wave's t = tw + l16
  const int tlane = tw + l16;

  // Q B-fragments (n = l16 = t, k contiguous)
  bf16x8 qf[4];
#pragma unroll
  for (int kf = 0; kf < 4; ++kf)
    qf[kf] = *(const bf16x8*)(qbase + (size_t)tlane * 128 + kf * 32 + quad * 8);

  f32x4 o[8] = {};
  f32x4 lacc = {0.f, 0.f, 0.f, 0.f};

  // prologue: issue K(0) then V(0)  (order matters for the vmcnt counts)
#pragma unroll
  for (int s = 0; s < 4; ++s) {
    gload_lds16(kp[s], sK + (wave * 4 + s) * 1024);
    kp[s] += 64 * 128;
  }
#pragma unroll
  for (int s = 0; s < 4; ++s) {
    gload_lds16(vp[s], sV + (wave * 4 + s) * 1024);
    vp[s] += 64;
  }

#pragma unroll 1
  for (int si = 0; si <= Q; ++si) {
    const int s0 = si * 64;
    // outstanding: K(si) 4 oldest + V(si) 4 -> retire K(si)
    asm volatile("s_waitcnt vmcnt(4)" ::: "memory");
    __builtin_amdgcn_s_barrier();                  // all waves' K(si) in sK
    asm volatile("" ::: "memory");

    const bool diag = (si == Q);
    const int nfmax = diag ? wave : 3;        // skip fully-masked s-frags
    const int kmax = diag ? (wave >> 1) : 1;

    // S^T = K Q^T : A = K (m=s), B = Q (n=t). C: col=t=l16, row=s=quad*4+reg
    f32x4 sacc[4];
    __builtin_amdgcn_s_setprio(1);
#pragma unroll
    for (int nf = 0; nf < 4; ++nf) {
      if (nf <= nfmax) {
        const int sr = nf * 16 + l16;
        f32x4 a = {0.f, 0.f, 0.f, 0.f};
#pragma unroll
        for (int kf = 0; kf < 4; ++kf) {
          const bf16x8 kfr =
              *(const bf16x8*)(sK + sr * 256 + (((kf * 4 + quad) ^ (sr & 15)) << 4));
          a = MFMA_BF16(kfr, qf[kf], a);
        }
        sacc[nf] = a;
      }
    }
    __builtin_amdgcn_s_setprio(0);

    asm volatile("" ::: "memory");
    __builtin_amdgcn_s_barrier();                  // sK free for overwrite
    asm volatile("" ::: "memory");
    if (si < Q) {                                  // K(si+1) lands under softmax+PV
#pragma unroll
      for (int s = 0; s < 4; ++s) {
        gload_lds16(kp[s], sK + (wave * 4 + s) * 1024);
        kp[s] += 64 * 128;
      }
    }

    // poly softcap (L2E folded) + fixed-offset exp (no max, no rescale) + mask
#pragma unroll
    for (int nf = 0; nf < 4; ++nf) {
      if (nf <= nfmax) {
        const f32x4 xv = sacc[nf];
        const f32x4 u = xv * xv;
        f32x4 t = u * (-B3) + B2;
        t = u * t + (-B1);
        t = u * t + L2E;                  // t = log2(e) * tanh(x/50)*50 / x
        f32x4 pv;
#pragma unroll
        for (int i = 0; i < 4; ++i) pv[i] = rexp2(fmaf(xv[i], t[i], -C50));
        if (diag) {
#pragma unroll
          for (int i = 0; i < 4; ++i) {
            const int sg = s0 + nf * 16 + quad * 4 + i;
            if (sg > tlane) pv[i] = 0.0f;
          }
        }
        sacc[nf] = pv;
        lacc += pv;
      }
    }

    // pack P columns to bf16x2 dwords (per-lane)
    unsigned pkd[4][2];
#pragma unroll
    for (int nf = 0; nf < 4; ++nf) {
      if (nf <= nfmax) {
        pkd[nf][0] = pk2(sacc[nf][0], sacc[nf][1]);
        pkd[nf][1] = pk2(sacc[nf][2], sacc[nf][3]);
      } else {
        pkd[nf][0] = 0u; pkd[nf][1] = 0u;
      }
    }

    // P^T B-fragments via bpermute (no sV dependency -> before the V wait)
    union { int d[4]; bf16x8 v; } pb[2];
#pragma unroll
    for (int c2 = 0; c2 < 2; ++c2) {
      if (c2 <= kmax) {
        const int lo = (quad >> 1);  // selects nf = 2*c2 + (quad>>1)
        const int dA0 = __builtin_amdgcn_ds_bpermute(bp_a0, (int)pkd[2 * c2][0]);
        const int dB0 = __builtin_amdgcn_ds_bpermute(bp_a0, (int)pkd[2 * c2 + 1][0]);
        const int dA1 = __builtin_amdgcn_ds_bpermute(bp_a0, (int)pkd[2 * c2][1]);
        const int dB1 = __builtin_amdgcn_ds_bpermute(bp_a0, (int)pkd[2 * c2 + 1][1]);
        const int dA2 = __builtin_amdgcn_ds_bpermute(bp_a1, (int)pkd[2 * c2][0]);
        const int dB2 = __builtin_amdgcn_ds_bpermute(bp_a1, (int)pkd[2 * c2 + 1][0]);
        const int dA3 = __builtin_amdgcn_ds_bpermute(bp_a1, (int)pkd[2 * c2][1]);
        const int dB3 = __builtin_amdgcn_ds_bpermute(bp_a1, (int)pkd[2 * c2 + 1][1]);
        pb[c2].d[0] = lo ? dB0 : dA0;
        pb[c2].d[1] = lo ? dB1 : dA1;
        pb[c2].d[2] = lo ? dB2 : dA2;
        pb[c2].d[3] = lo ? dB3 : dA3;
      }
    }

    // outstanding: V(si) 4 oldest + K(si+1) 4 -> retire V(si); last iter: drain
    if (si < Q) {
      asm volatile("s_waitcnt vmcnt(4)" ::: "memory");
    } else {
      asm volatile("s_waitcnt vmcnt(0)" ::: "memory");
    }
    __builtin_amdgcn_s_barrier();                  // all waves' V(si) in sV
    asm volatile("" ::: "memory");

    // O^T += V^T P^T : per chunk c2 (k = s 32-wide)
#pragma unroll
    for (int c2 = 0; c2 < 2; ++c2) {
      if (c2 <= kmax) {
        __builtin_amdgcn_s_setprio(1);
#pragma unroll
        for (int nfo = 0; nfo < 8; ++nfo) {
          const int hr = nfo * 16 + l16;
          const bf16x8 vb =
              *(const bf16x8*)(sV + hr * 128 + (((c2 * 4 + quad) ^ (hr & 7)) << 4));
          o[nfo] = MFMA_BF16(vb, pb[c2].v, o[nfo]);
        }
        __builtin_amdgcn_s_setprio(0);
      }
    }

    asm volatile("" ::: "memory");
    __builtin_amdgcn_s_barrier();                  // sV free for overwrite
    asm volatile("" ::: "memory");
    if (si < Q) {                                  // V(si+1) lands under next QK^T
#pragma unroll
      for (int s = 0; s < 4; ++s) {
        gload_lds16(vp[s], sV + (wave * 4 + s) * 1024);
        vp[s] += 64;
      }
    }
  }

  // epilogue: reduce l across quads (same t = l16 in each 16-lane group)
  float lsum = lacc[0] + lacc[1] + lacc[2] + lacc[3];
  lsum += __shfl_xor(lsum, 16);
  lsum += __shfl_xor(lsum, 32);
  const float inv = 1.0f / lsum;
  u16* d = enc + (((size_t)b * 2048 + tlane) * 16 + n) * 128 + quad * 4;
#pragma unroll
  for (int nfo = 0; nfo < 8; ++nfo) {
    uint2 st;
    st.x = (unsigned)f2b(o[nfo][0] * inv) | ((unsigned)f2b(o[nfo][1] * inv) << 16);
    st.y = (unsigned)f2b(o[nfo][2] * inv) | ((unsigned)f2b(o[nfo][3] * inv) << 16);
    *(uint2*)(d + nfo * 16) = st;
  }
}

// ---------------- output projection GEMM: 256x128 tile, 8 waves, depth-2 pipeline, f32 out ----
// Same structure as gemm_qkv (BM=256, BN=128 so grid stays 16x16 = 256 blocks
// = 1/CU).  LDS: 2 x (A 32KB + B 16KB) = 96KB.  6 loads/thread/stage ->
// s_waitcnt vmcnt(6).
__global__ __launch_bounds__(512, 2) void gemm_out(const u16* __restrict__ A,
                                                   const u16* __restrict__ Bt,
                                                   float* __restrict__ C) {
  __shared__ __align__(16) u16 sA[2][16384];  // [buf][256 rows x 64 cols]
  __shared__ __align__(16) u16 sB[2][8192];   // [buf][128 rows x 64 cols]
  const int m0 = blockIdx.x * 256;
  const int n0 = blockIdx.y * 128;
  const int tid = threadIdx.x;
  const int wave = tid >> 6, lane = tid & 63;
  const int wm = wave >> 2, wn = wave & 3;       // 2 M-waves x 4 N-waves (per-wave 128x32)
  const int quad = lane >> 4, l16 = lane & 15;
  const int srow = lane >> 3;
  const int sch = (lane & 7) ^ srow;

  f32x4 acc[8][2] = {};

  auto STAGE = [&](int kt, int bsel) {
    const int k0 = kt * 64;
#pragma unroll
    for (int s = 0; s < 4; ++s) {
      const int ia = wave * 4 + s;               // 0..31
      const int row = ia * 8 + srow;             // 0..255
      gload_lds16(A + (size_t)(m0 + row) * 2048 + k0 + sch * 8,
                  (char*)&sA[bsel][0] + ia * 1024);
    }
#pragma unroll
    for (int s = 0; s < 2; ++s) {
      const int ib = wave * 2 + s;               // 0..15
      const int row = ib * 8 + srow;             // 0..127
      gload_lds16(Bt + (size_t)(n0 + row) * 2048 + k0 + sch * 8,
                  (char*)&sB[bsel][0] + ib * 1024);
    }
  };

  auto COMPUTE = [&](int bsel) {
    const char* aB = (const char*)&sA[bsel][0];
    const char* bB = (const char*)&sB[bsel][0];
#pragma unroll
    for (int ks = 0; ks < 2; ++ks) {
      bf16x8 bfr[2];
#pragma unroll
      for (int nf = 0; nf < 2; ++nf) {
        const int Rb = wn * 32 + nf * 16 + l16;
        bfr[nf] = *(const bf16x8*)(bB + Rb * 128 + (((ks * 4 + quad) ^ (Rb & 7)) << 4));
      }
      __builtin_amdgcn_s_setprio(1);
#pragma unroll
      for (int mf = 0; mf < 8; ++mf) {
        const int R = wm * 128 + mf * 16 + l16;
        const bf16x8 af = *(const bf16x8*)(aB + R * 128 + (((ks * 4 + quad) ^ (R & 7)) << 4));
#pragma unroll
        for (int nf = 0; nf < 2; ++nf)
          acc[mf][nf] = MFMA_BF16(af, bfr[nf], acc[mf][nf]);
      }
      __builtin_amdgcn_s_setprio(0);
    }
  };

  STAGE(0, 0);
#pragma unroll 1
  for (int t = 0; t < 31; ++t) {
    STAGE(t + 1, (t + 1) & 1);
    asm volatile("s_waitcnt vmcnt(6)" ::: "memory");  // tile t landed (wave-local)
    __builtin_amdgcn_s_barrier();
    asm volatile("" ::: "memory");
    COMPUTE(t & 1);
    asm volatile("" ::: "memory");
    __builtin_amdgcn_s_barrier();
    asm volatile("" ::: "memory");
  }
  asm volatile("s_waitcnt vmcnt(0)" ::: "memory");
  __builtin_amdgcn_s_barrier();
  asm volatile("" ::: "memory");
  COMPUTE(1);  // tile 31

#pragma unroll
  for (int mf = 0; mf < 8; ++mf) {
    const int mm = m0 + wm * 128 + mf * 16 + quad * 4;
#pragma unroll
    for (int nf = 0; nf < 2; ++nf) {
      const int col = n0 + wn * 32 + nf * 16 + l16;
#pragma unroll
      for (int i = 0; i < 4; ++i) C[(size_t)(mm + i) * 2048 + col] = acc[mf][nf][i];
    }
  }
}

extern "C" void kernel_launch(void* const* d_in, const int* in_sizes, int n_in,
                              void* d_out, int out_size, void* d_ws, size_t ws_size,
                              hipStream_t stream) {
  (void)in_sizes; (void)n_in; (void)out_size; (void)ws_size;
  const float* x     = (const float*)d_in[0];
  const int*   posi  = (const int*)d_in[1];
  const float* w_q   = (const float*)d_in[3];
  const float* w_kv  = (const float*)d_in[4];
  const float* w_out = (const float*)d_in[5];
  float* out = (float*)d_out;

  u16* ws = (u16*)d_ws;
  u16* wqkvt = ws;
  u16* woutt = ws + (size_t)8388608;
  u16* qb    = ws + (size_t)12582912;
  u16* kb    = ws + (size_t)20971520;
  u16* vtb   = ws + (size_t)25165824;
  u16* encb  = ws + (size_t)29360128;
  u16* xb    = encb;  // alias: consumed by gemm_qkv before attn writes enc

  prep<<<20480, 256, 0, stream>>>(x, xb, w_q, w_kv, w_out, wqkvt, woutt);
  gemm_qkv<<<dim3(16, 16), 512, 0, stream>>>(xb, wqkvt, qb, kb, vtb);
  rope_kernel<<<12288, 256, 0, stream>>>(qb, kb, posi);
  attn_fused<<<1024, 256, 0, stream>>>(qb, kb, vtb, encb);
  gemm_out<<<dim3(16, 16), 512, 0, stream>>>(encb, woutt, out);
}